// Round 5
// baseline (429.194 us; speedup 1.0000x reference)
//
#include <hip/hip_runtime.h>
#include <hip/hip_bf16.h>
#include <stdint.h>

// Problem dims (fixed by reference): B=4096, I=2048, H=2048, K=I+H=4096
#define BB 4096
#define II 2048
#define HH 2048
#define KK 4096

typedef __bf16 bf16x8 __attribute__((ext_vector_type(8)));
typedef float f32x4 __attribute__((ext_vector_type(4)));

typedef __attribute__((address_space(3))) uint32_t lds_u32;
typedef const __attribute__((address_space(1))) uint32_t glb_u32;

__device__ __forceinline__ void load_lds16(const void* g, void* l) {
    __builtin_amdgcn_global_load_lds((glb_u32*)g, (lds_u32*)l, 16, 0, 0);
}

// ---------------------------------------------------------------------------
// prep_weights: sign(w) -> bf16 (+-1.0 / 0.0), and sum |w| -> scales[which]
// ---------------------------------------------------------------------------
__global__ __launch_bounds__(256) void prep_weights(
    const float* __restrict__ w_r, const float* __restrict__ w_z,
    const float* __restrict__ w_n,
    __hip_bfloat16* __restrict__ sign_rz, __hip_bfloat16* __restrict__ sign_n,
    float* __restrict__ scales)
{
    const int which = blockIdx.y;
    const float* w = (which == 0) ? w_r : (which == 1 ? w_z : w_n);
    __hip_bfloat16* dst = (which == 0) ? sign_rz
                        : (which == 1 ? sign_rz + (size_t)HH * KK : sign_n);

    const int total4 = HH * KK / 4;
    const int tid = blockIdx.x * 256 + threadIdx.x;
    const int stride = gridDim.x * 256;

    float s = 0.0f;
    for (int i = tid; i < total4; i += stride) {
        float4 v = reinterpret_cast<const float4*>(w)[i];
        s += fabsf(v.x) + fabsf(v.y) + fabsf(v.z) + fabsf(v.w);
        ushort4 o;
        o.x = (v.x == 0.0f) ? 0 : (ushort)(0x3F80u | ((__float_as_uint(v.x) >> 16) & 0x8000u));
        o.y = (v.y == 0.0f) ? 0 : (ushort)(0x3F80u | ((__float_as_uint(v.y) >> 16) & 0x8000u));
        o.z = (v.z == 0.0f) ? 0 : (ushort)(0x3F80u | ((__float_as_uint(v.z) >> 16) & 0x8000u));
        o.w = (v.w == 0.0f) ? 0 : (ushort)(0x3F80u | ((__float_as_uint(v.w) >> 16) & 0x8000u));
        *reinterpret_cast<ushort4*>(&dst[(size_t)i * 4]) = o;
    }

    #pragma unroll
    for (int o = 32; o > 0; o >>= 1) s += __shfl_xor(s, o);
    __shared__ float red[4];
    const int wid = threadIdx.x >> 6, lane = threadIdx.x & 63;
    if (lane == 0) red[wid] = s;
    __syncthreads();
    if (threadIdx.x == 0)
        atomicAdd(&scales[which], red[0] + red[1] + red[2] + red[3]);
}

// ---------------------------------------------------------------------------
// prep_inputs: x -> bf16 into combined[:,0:2048] and combined2[:,0:2048];
//              hidden -> bf16 into combined[:,2048:4096]
// ---------------------------------------------------------------------------
__global__ __launch_bounds__(256) void prep_inputs(
    const float* __restrict__ x, const float* __restrict__ hidden,
    __hip_bfloat16* __restrict__ combined, __hip_bfloat16* __restrict__ combined2)
{
    const int which = blockIdx.y;
    const float* src = which ? hidden : x;
    const int total4 = BB * II / 4;
    const int tid = blockIdx.x * 256 + threadIdx.x;
    const int stride = gridDim.x * 256;

    for (int i = tid; i < total4; i += stride) {
        float4 v = reinterpret_cast<const float4*>(src)[i];
        int e = i * 4;
        int row = e >> 11;
        int col = e & 2047;
        union { ushort4 u; __hip_bfloat16 h[4]; } o;
        o.h[0] = __float2bfloat16(v.x);
        o.h[1] = __float2bfloat16(v.y);
        o.h[2] = __float2bfloat16(v.z);
        o.h[3] = __float2bfloat16(v.w);
        size_t off = (size_t)row * KK + (which ? 2048 + col : col);
        *reinterpret_cast<ushort4*>(&combined[off]) = o.u;
        if (!which)
            *reinterpret_cast<ushort4*>(&combined2[off]) = o.u;
    }
}

// ---------------------------------------------------------------------------
// m201 8-phase GEMM, 256x256 tile, BK=64, 512 thr (8 waves 2Mx4N), wave 128x64.
// UNIFORM phases: {ds_read at TOP | stage 1 half | mid barrier | lgkmcnt(0) |
// setprio(1) 16 MFMA setprio(0) | [vmcnt(4) at P3/P7] | trailing barrier}.
// Publication: P3-end vmcnt(4)+barrier publishes B(O)+A(O) (keeps B(E2));
//              P7-end publishes B(E2)+A(E2) (keeps B(O2)).
// EPI=1: r||z epilogue (N=4096). EPI=2: raw fp32 partial store (split-K).
// LDS swizzle byte ^= (row&7)<<4 via pre-swizzled global source (rule #21).
// ---------------------------------------------------------------------------
#define RD_A(ab, m0)                                                           \
    _Pragma("unroll") for (int mm = 0; mm < 2; mm++)                           \
    _Pragma("unroll") for (int k = 0; k < 2; k++)                              \
        afr[mm][k] = *(const bf16x8*)((ab) + arowb[(m0) + mm] + colb[k]);

#define RD_B(bb)                                                               \
    _Pragma("unroll") for (int n = 0; n < 4; n++)                              \
    _Pragma("unroll") for (int k = 0; k < 2; k++)                              \
        bfrag[n][k] = *(const bf16x8*)((bb) + browb[n] + colb[k]);

#define DO_MFMA(m0)                                                            \
    _Pragma("unroll") for (int mm = 0; mm < 2; mm++)                           \
    _Pragma("unroll") for (int n = 0; n < 4; n++)                              \
    _Pragma("unroll") for (int k = 0; k < 2; k++)                              \
        acc[(m0) + mm][n] = __builtin_amdgcn_mfma_f32_16x16x32_bf16(           \
            afr[mm][k], bfrag[n][k], acc[(m0) + mm][n], 0, 0, 0);

#define MID_SYNC()                                                             \
    __builtin_amdgcn_s_barrier();                                              \
    asm volatile("s_waitcnt lgkmcnt(0)" ::: "memory");                         \
    __builtin_amdgcn_s_setprio(1);

#define TAIL_PLAIN()                                                           \
    __builtin_amdgcn_s_setprio(0);                                             \
    __builtin_amdgcn_s_barrier();

#define TAIL_VMCNT()                                                           \
    __builtin_amdgcn_s_setprio(0);                                             \
    asm volatile("s_waitcnt vmcnt(4)" ::: "memory");                           \
    __builtin_amdgcn_s_barrier();

template <int EPI, int NIT>
__global__ __launch_bounds__(512, 2) void gemm8p(
    const __hip_bfloat16* __restrict__ A,    // [4096][4096] bf16
    const __hip_bfloat16* __restrict__ Bw,   // [N][4096] bf16 (signs)
    const float* __restrict__ scales,
    const float* __restrict__ b_r, const float* __restrict__ b_z,
    const float* __restrict__ hidden,        // [4096][2048] f32
    float* __restrict__ z_buf,               // [4096][2048] f32
    __hip_bfloat16* __restrict__ combined2,  // [4096][4096] bf16
    float* __restrict__ part0,               // split-K partial, slice 0
    float* __restrict__ part1)               // split-K partial, slice 1
{
    constexpr int TMASK = 2 * NIT - 1;

    __shared__ __align__(16) char smem[131072];  // A dbuf 64KB | B dbuf 64KB

    const int T = threadIdx.x;
    const int lane = T & 63;
    const int wid = T >> 6;
    const int wr = wid >> 2;    // 0..1
    const int wc = wid & 3;     // 0..3

    // bijective XCD swizzle over the z-slice's 2D grid (nwg % 8 == 0)
    const int nbn = gridDim.x;
    const int nwg = nbn * gridDim.y;
    const int bid = blockIdx.y * nbn + blockIdx.x;
    const int swz = (bid & 7) * (nwg >> 3) + (bid >> 3);
    const int bn = swz % nbn;
    const int bm = swz / nbn;
    // K-slice base: each slice covers NIT iterations x 2 tiles x 64 = NIT*128
    const int kb = blockIdx.z * (NIT * 128);

    // fragment read byte-offsets (swizzled)
    int arowb[8], browb[4], colb[2];
    #pragma unroll
    for (int m = 0; m < 8; m++) arowb[m] = (wr * 128 + m * 16 + (lane & 15)) << 7;
    #pragma unroll
    for (int n = 0; n < 4; n++) browb[n] = (wc * 64 + n * 16 + (lane & 15)) << 7;
    #pragma unroll
    for (int k = 0; k < 2; k++)
        colb[k] = (k * 64 + ((lane >> 4) << 4)) ^ ((lane & 7) << 4);

    // staging: thread T covers row (T>>3), source col pre-inverse-swizzled
    const int srow = T >> 3;                       // 0..63
    const int scol = ((T & 7) ^ (srow & 7)) << 3;  // element offset
    const __hip_bfloat16* gA = A  + (size_t)(bm * 256 + srow) * KK + kb + scol;
    const __hip_bfloat16* gB = Bw + (size_t)(bn * 256 + srow) * KK + kb + scol;

    auto stA = [&](int tile, int h) {
        const __hip_bfloat16* g = gA + (size_t)(h * 128) * KK + ((tile & TMASK) << 6);
        char* l = smem + (tile & 1) * 32768 + h * 16384 + T * 16;
        load_lds16(g, l);
        load_lds16(g + (size_t)64 * KK, l + 8192);
    };
    auto stB = [&](int tile, int h) {
        const __hip_bfloat16* g = gB + (size_t)(h * 128) * KK + ((tile & TMASK) << 6);
        char* l = smem + 65536 + (tile & 1) * 32768 + h * 16384 + T * 16;
        load_lds16(g, l);
        load_lds16(g + (size_t)64 * KK, l + 8192);
    };

    f32x4 acc[8][4] = {};

    // prologue: B(0), A(0), B(1); publish B(0)+A(0), keep B(1) in flight
    stB(0, 0); stB(0, 1); stA(0, 0); stA(0, 1); stB(1, 0); stB(1, 1);
    asm volatile("s_waitcnt vmcnt(4)" ::: "memory");
    __builtin_amdgcn_s_barrier();

    const char* ab0 = smem;
    const char* ab1 = smem + 32768;
    const char* bb0 = smem + 65536;
    const char* bb1 = smem + 65536 + 32768;

    for (int t = 0; t < NIT; ++t) {
        const int O  = 2 * t + 1;
        const int E2 = 2 * t + 2;
        const int O2 = 2 * t + 3;

        bf16x8 bfrag[4][2];
        bf16x8 afr[2][2];

        // ---- P0 (tile E, m0-1): reads at top; stage A(O)h0
        RD_B(bb0); RD_A(ab0, 0);
        stA(O, 0);
        asm volatile("s_waitcnt lgkmcnt(8)" ::: "memory");
        MID_SYNC(); DO_MFMA(0); TAIL_PLAIN();

        // ---- P1: m2-3; stage A(O)h1
        RD_A(ab0, 2);
        stA(O, 1);
        MID_SYNC(); DO_MFMA(2); TAIL_PLAIN();

        // ---- P2: m4-5; stage B(E2)h0
        RD_A(ab0, 4);
        stB(E2, 0);
        MID_SYNC(); DO_MFMA(4); TAIL_PLAIN();

        // ---- P3: m6-7; stage B(E2)h1; publish B(O)+A(O), keep B(E2)
        RD_A(ab0, 6);
        stB(E2, 1);
        MID_SYNC(); DO_MFMA(6); TAIL_VMCNT();

        // ---- P4 (tile O, m0-1): stage A(E2)h0
        RD_B(bb1); RD_A(ab1, 0);
        stA(E2, 0);
        asm volatile("s_waitcnt lgkmcnt(8)" ::: "memory");
        MID_SYNC(); DO_MFMA(0); TAIL_PLAIN();

        // ---- P5: m2-3; stage A(E2)h1
        RD_A(ab1, 2);
        stA(E2, 1);
        MID_SYNC(); DO_MFMA(2); TAIL_PLAIN();

        // ---- P6: m4-5; stage B(O2)h0
        RD_A(ab1, 4);
        stB(O2, 0);
        MID_SYNC(); DO_MFMA(4); TAIL_PLAIN();

        // ---- P7: m6-7; stage B(O2)h1; publish B(E2)+A(E2), keep B(O2)
        RD_A(ab1, 6);
        stB(O2, 1);
        MID_SYNC(); DO_MFMA(6); TAIL_VMCNT();
    }

    asm volatile("s_waitcnt vmcnt(0)" ::: "memory");
    __builtin_amdgcn_sched_barrier(0);

    // ---- epilogue
    if (EPI == 1) {
        const float inv_cnt = 1.0f / ((float)HH * (float)KK);
        const bool is_r = (bn < 8);
        const float scale = (is_r ? scales[0] : scales[1]) * inv_cnt;
        const float* bias = is_r ? b_r : b_z;
        #pragma unroll
        for (int m = 0; m < 8; m++) {
            #pragma unroll
            for (int n = 0; n < 4; n++) {
                const int col = bn * 256 + wc * 64 + n * 16 + (lane & 15);
                const int j = is_r ? col : col - 2048;
                const float bj = bias[j];
                #pragma unroll
                for (int i = 0; i < 4; i++) {
                    const int row = bm * 256 + wr * 128 + m * 16 + ((lane >> 4) << 2) + i;
                    float pre = acc[m][n][i] * scale + bj;
                    float sg = 1.0f / (1.0f + __expf(-pre));
                    if (is_r) {
                        float rh = sg * hidden[(size_t)row * HH + j];
                        combined2[(size_t)row * KK + 2048 + j] = __float2bfloat16(rh);
                    } else {
                        z_buf[(size_t)row * HH + j] = sg;
                    }
                }
            }
        }
    } else {
        float* pdst = (blockIdx.z == 0) ? part0 : part1;
        #pragma unroll
        for (int m = 0; m < 8; m++) {
            #pragma unroll
            for (int n = 0; n < 4; n++) {
                const int col = bn * 256 + wc * 64 + n * 16 + (lane & 15);
                #pragma unroll
                for (int i = 0; i < 4; i++) {
                    const int row = bm * 256 + wr * 128 + m * 16 + ((lane >> 4) << 2) + i;
                    pdst[(size_t)row * HH + col] = acc[m][n][i];
                }
            }
        }
    }
}

// ---------------------------------------------------------------------------
// combine: out = (1-z)*hidden + z*tanh((p0+p1)*scale_n + b_n)
// ---------------------------------------------------------------------------
__global__ __launch_bounds__(256) void combine(
    const float* __restrict__ p0, const float* __restrict__ p1,
    const float* __restrict__ z_buf, const float* __restrict__ hidden,
    const float* __restrict__ scales, const float* __restrict__ b_n,
    float* __restrict__ out)
{
    const float scale = scales[2] * (1.0f / ((float)HH * (float)KK));
    const int total4 = BB * HH / 4;
    const int tid = blockIdx.x * 256 + threadIdx.x;
    const int stride = gridDim.x * 256;

    for (int i = tid; i < total4; i += stride) {
        float4 a = reinterpret_cast<const float4*>(p0)[i];
        float4 b = reinterpret_cast<const float4*>(p1)[i];
        float4 z = reinterpret_cast<const float4*>(z_buf)[i];
        float4 h = reinterpret_cast<const float4*>(hidden)[i];
        float4 bn = reinterpret_cast<const float4*>(b_n)[(i * 4 & 2047) >> 2];
        float4 o;
        o.x = (1.0f - z.x) * h.x + z.x * tanhf((a.x + b.x) * scale + bn.x);
        o.y = (1.0f - z.y) * h.y + z.y * tanhf((a.y + b.y) * scale + bn.y);
        o.z = (1.0f - z.z) * h.z + z.z * tanhf((a.z + b.z) * scale + bn.z);
        o.w = (1.0f - z.w) * h.w + z.w * tanhf((a.w + b.w) * scale + bn.w);
        reinterpret_cast<float4*>(out)[i] = o;
    }
}

// ---------------------------------------------------------------------------
extern "C" void kernel_launch(void* const* d_in, const int* in_sizes, int n_in,
                              void* d_out, int out_size, void* d_ws, size_t ws_size,
                              hipStream_t stream) {
    const float* x      = (const float*)d_in[0];
    const float* hidden = (const float*)d_in[1];
    const float* w_r    = (const float*)d_in[2];
    const float* b_r    = (const float*)d_in[3];
    const float* w_z    = (const float*)d_in[4];
    const float* b_z    = (const float*)d_in[5];
    const float* w_n    = (const float*)d_in[6];
    const float* b_n    = (const float*)d_in[7];
    float* out = (float*)d_out;

    char* ws = (char*)d_ws;
    size_t off = 0;
    float* scales = (float*)(ws + off);                 off += 256;
    __hip_bfloat16* combined  = (__hip_bfloat16*)(ws + off); off += (size_t)BB * KK * 2;
    __hip_bfloat16* combined2 = (__hip_bfloat16*)(ws + off); off += (size_t)BB * KK * 2;
    __hip_bfloat16* sign_rz   = (__hip_bfloat16*)(ws + off); off += (size_t)2 * HH * KK * 2;
    __hip_bfloat16* sign_n    = (__hip_bfloat16*)(ws + off); off += (size_t)HH * KK * 2;
    float* z_buf = (float*)(ws + off);                  off += (size_t)BB * HH * 4;
    // split-K partials: slice 0 -> d_out (scratch until combine); slice 1
    // aliases sign_rz (dead after GEMM1, 64MB >= 32MB needed)
    float* part1 = (float*)sign_rz;

    hipMemsetAsync(scales, 0, 3 * sizeof(float), stream);

    prep_weights<<<dim3(512, 3), 256, 0, stream>>>(w_r, w_z, w_n,
                                                   sign_rz, sign_n, scales);
    prep_inputs<<<dim3(1024, 2), 256, 0, stream>>>(x, hidden, combined, combined2);

    // GEMM1: r||z  (N = 4096), full K, 256 blocks = 1/CU
    gemm8p<1, 32><<<dim3(16, 16, 1), 512, 0, stream>>>(
        combined, sign_rz, scales, b_r, b_z, hidden, z_buf, combined2,
        out, part1);

    // GEMM2: n  (N = 2048), split-K=2, 8x16x2 = 256 blocks = 1/CU
    gemm8p<2, 16><<<dim3(8, 16, 2), 512, 0, stream>>>(
        combined2, sign_n, scales, b_r, b_z, hidden, z_buf, combined2,
        out, part1);

    // fuse scale+bias+tanh+GRU blend
    combine<<<dim3(2048), 256, 0, stream>>>(out, part1, z_buf, hidden,
                                            scales, b_n, out);
}

// Round 6
// 422.347 us; speedup vs baseline: 1.0162x; 1.0162x over previous
//
#include <hip/hip_runtime.h>
#include <hip/hip_bf16.h>
#include <stdint.h>

// Problem dims (fixed by reference): B=4096, I=2048, H=2048, K=I+H=4096
#define BB 4096
#define II 2048
#define HH 2048
#define KK 4096

typedef __bf16 bf16x8 __attribute__((ext_vector_type(8)));
typedef float f32x4 __attribute__((ext_vector_type(4)));

typedef __attribute__((address_space(3))) uint32_t lds_u32;
typedef const __attribute__((address_space(1))) uint32_t glb_u32;

__device__ __forceinline__ void load_lds16(const void* g, void* l) {
    __builtin_amdgcn_global_load_lds((glb_u32*)g, (lds_u32*)l, 16, 0, 0);
}

// ---------------------------------------------------------------------------
// prep_weights: sign(w) -> bf16 (+-1.0 / 0.0), and sum |w| -> scales[which]
// ---------------------------------------------------------------------------
__global__ __launch_bounds__(256) void prep_weights(
    const float* __restrict__ w_r, const float* __restrict__ w_z,
    const float* __restrict__ w_n,
    __hip_bfloat16* __restrict__ sign_rz, __hip_bfloat16* __restrict__ sign_n,
    float* __restrict__ scales)
{
    const int which = blockIdx.y;
    const float* w = (which == 0) ? w_r : (which == 1 ? w_z : w_n);
    __hip_bfloat16* dst = (which == 0) ? sign_rz
                        : (which == 1 ? sign_rz + (size_t)HH * KK : sign_n);

    const int total4 = HH * KK / 4;
    const int tid = blockIdx.x * 256 + threadIdx.x;
    const int stride = gridDim.x * 256;

    float s = 0.0f;
    for (int i = tid; i < total4; i += stride) {
        float4 v = reinterpret_cast<const float4*>(w)[i];
        s += fabsf(v.x) + fabsf(v.y) + fabsf(v.z) + fabsf(v.w);
        ushort4 o;
        o.x = (v.x == 0.0f) ? 0 : (ushort)(0x3F80u | ((__float_as_uint(v.x) >> 16) & 0x8000u));
        o.y = (v.y == 0.0f) ? 0 : (ushort)(0x3F80u | ((__float_as_uint(v.y) >> 16) & 0x8000u));
        o.z = (v.z == 0.0f) ? 0 : (ushort)(0x3F80u | ((__float_as_uint(v.z) >> 16) & 0x8000u));
        o.w = (v.w == 0.0f) ? 0 : (ushort)(0x3F80u | ((__float_as_uint(v.w) >> 16) & 0x8000u));
        *reinterpret_cast<ushort4*>(&dst[(size_t)i * 4]) = o;
    }

    #pragma unroll
    for (int o = 32; o > 0; o >>= 1) s += __shfl_xor(s, o);
    __shared__ float red[4];
    const int wid = threadIdx.x >> 6, lane = threadIdx.x & 63;
    if (lane == 0) red[wid] = s;
    __syncthreads();
    if (threadIdx.x == 0)
        atomicAdd(&scales[which], red[0] + red[1] + red[2] + red[3]);
}

// ---------------------------------------------------------------------------
// prep_inputs: x -> bf16 into combined[:,0:2048] and combined2[:,0:2048];
//              hidden -> bf16 into combined[:,2048:4096]
// ---------------------------------------------------------------------------
__global__ __launch_bounds__(256) void prep_inputs(
    const float* __restrict__ x, const float* __restrict__ hidden,
    __hip_bfloat16* __restrict__ combined, __hip_bfloat16* __restrict__ combined2)
{
    const int which = blockIdx.y;
    const float* src = which ? hidden : x;
    const int total4 = BB * II / 4;
    const int tid = blockIdx.x * 256 + threadIdx.x;
    const int stride = gridDim.x * 256;

    for (int i = tid; i < total4; i += stride) {
        float4 v = reinterpret_cast<const float4*>(src)[i];
        int e = i * 4;
        int row = e >> 11;
        int col = e & 2047;
        union { ushort4 u; __hip_bfloat16 h[4]; } o;
        o.h[0] = __float2bfloat16(v.x);
        o.h[1] = __float2bfloat16(v.y);
        o.h[2] = __float2bfloat16(v.z);
        o.h[3] = __float2bfloat16(v.w);
        size_t off = (size_t)row * KK + (which ? 2048 + col : col);
        *reinterpret_cast<ushort4*>(&combined[off]) = o.u;
        if (!which)
            *reinterpret_cast<ushort4*>(&combined2[off]) = o.u;
    }
}

// ---------------------------------------------------------------------------
// 8-phase pipelined GEMM, 256x256 tile, BK=64, 512 thr (8 waves 2Mx4N),
// per-wave 128x64 C. SOFTWARE-PIPELINED fragments: phase p issues ds_reads
// for phase p+1 (afrX/afrY ping-pong); MFMA consumes registers read at p-1.
// NO hand lgkmcnt — compiler emits exactly-counted waits before each MFMA
// (covers prev-phase reads only, leaves this phase's reads in flight).
// B frags single-buffered: read at P0/P4 (first-use phase, 2 short waits/iter).
// ONE barrier per phase. Counted vmcnt(2) only at P2/P6 tails (publication:
// P2 -> B(O)+A(O) visible for P3/P4 reads; P6 -> B(E2)+A(E2) for P7/P0).
// WAR audit: every staged buffer's prior reads are compiler-fenced >=1 phase
// and >=1 barrier before the overwriting global_load_lds issues.
// LDS swizzle byte ^= (row&7)<<4 via pre-swizzled global source (rule #21).
// EPI=1: r||z epilogue (N=4096). EPI=2: raw fp32 partial store (split-K).
// ---------------------------------------------------------------------------
#define RD_B8(BOFS)                                                            \
    _Pragma("unroll") for (int n = 0; n < 4; n++) {                            \
        bf[n][0] = *(const bf16x8*)(pb0 + (BOFS) + n * 2048);                  \
        bf[n][1] = *(const bf16x8*)(pb1 + (BOFS) + n * 2048);                  \
    }

#define RD_A2(DST, AOFS, m0)                                                   \
    _Pragma("unroll") for (int mm = 0; mm < 2; mm++) {                         \
        DST[mm][0] = *(const bf16x8*)(pa0 + (AOFS) + ((m0) + mm) * 2048);      \
        DST[mm][1] = *(const bf16x8*)(pa1 + (AOFS) + ((m0) + mm) * 2048);      \
    }

#define DO_MFMA(AF, m0)                                                        \
    __builtin_amdgcn_s_setprio(1);                                             \
    _Pragma("unroll") for (int mm = 0; mm < 2; mm++)                           \
    _Pragma("unroll") for (int n = 0; n < 4; n++)                              \
    _Pragma("unroll") for (int k = 0; k < 2; k++)                              \
        acc[(m0) + mm][n] = __builtin_amdgcn_mfma_f32_16x16x32_bf16(           \
            AF[mm][k], bf[n][k], acc[(m0) + mm][n], 0, 0, 0);                  \
    __builtin_amdgcn_s_setprio(0);

#define BAR() __builtin_amdgcn_s_barrier();
#define VM2() asm volatile("s_waitcnt vmcnt(2)" ::: "memory");

template <int EPI, int NIT>
__global__ __launch_bounds__(512, 2) void gemm8p(
    const __hip_bfloat16* __restrict__ A,    // [4096][4096] bf16
    const __hip_bfloat16* __restrict__ Bw,   // [N][4096] bf16 (signs)
    const float* __restrict__ scales,
    const float* __restrict__ b_r, const float* __restrict__ b_z,
    const float* __restrict__ hidden,        // [4096][2048] f32
    float* __restrict__ z_buf,               // [4096][2048] f32
    __hip_bfloat16* __restrict__ combined2,  // [4096][4096] bf16
    float* __restrict__ part0,               // split-K partial, slice 0
    float* __restrict__ part1)               // split-K partial, slice 1
{
    constexpr int TMASK = 2 * NIT - 1;

    __shared__ __align__(16) char smem[131072];  // A dbuf 64KB | B dbuf 64KB

    const int T = threadIdx.x;
    const int lane = T & 63;
    const int wid = T >> 6;
    const int wr = wid >> 2;    // 0..1
    const int wc = wid & 3;     // 0..3

    // bijective XCD swizzle over the z-slice's 2D grid (nwg % 8 == 0)
    const int nbn = gridDim.x;
    const int nwg = nbn * gridDim.y;
    const int bid = blockIdx.y * nbn + blockIdx.x;
    const int swz = (bid & 7) * (nwg >> 3) + (bid >> 3);
    const int bn = swz % nbn;
    const int bm = swz / nbn;
    // K-slice base: each slice covers NIT iterations x 2 tiles x 64 = NIT*128
    const int kb = blockIdx.z * (NIT * 128);

    // fragment read base pointers (swizzled); per-frag offsets are imm-folded
    const int colb0 = (((lane >> 4) << 4)) ^ ((lane & 7) << 4);
    const int colb1 = (64 + ((lane >> 4) << 4)) ^ ((lane & 7) << 4);
    const char* pa0 = smem + ((wr * 128 + (lane & 15)) << 7) + colb0;
    const char* pa1 = smem + ((wr * 128 + (lane & 15)) << 7) + colb1;
    const char* pb0 = smem + 65536 + ((wc * 64 + (lane & 15)) << 7) + colb0;
    const char* pb1 = smem + 65536 + ((wc * 64 + (lane & 15)) << 7) + colb1;

    // staging: thread T covers row (T>>3), source col pre-inverse-swizzled
    const int srow = T >> 3;                       // 0..63
    const int scol = ((T & 7) ^ (srow & 7)) << 3;  // element offset
    const __hip_bfloat16* gA = A  + (size_t)(bm * 256 + srow) * KK + kb + scol;
    const __hip_bfloat16* gB = Bw + (size_t)(bn * 256 + srow) * KK + kb + scol;

    auto stA = [&](int tile, int h) {
        const __hip_bfloat16* g = gA + (size_t)(h * 128) * KK + ((tile & TMASK) << 6);
        char* l = smem + (tile & 1) * 32768 + h * 16384 + T * 16;
        load_lds16(g, l);
        load_lds16(g + (size_t)64 * KK, l + 8192);
    };
    auto stB = [&](int tile, int h) {
        const __hip_bfloat16* g = gB + (size_t)(h * 128) * KK + ((tile & TMASK) << 6);
        char* l = smem + 65536 + (tile & 1) * 32768 + h * 16384 + T * 16;
        load_lds16(g, l);
        load_lds16(g + (size_t)64 * KK, l + 8192);
    };

    f32x4 acc[8][4] = {};
    bf16x8 bf[4][2];
    bf16x8 afrX[2][2], afrY[2][2];

    // prologue: stage B(0)->bb0, A(0)->ab0, B(1)->bb1; publish bb0+ab0,
    // keep B(1)'s 4 loads in flight (matches P7-end steady invariant).
    stB(0, 0); stB(0, 1); stA(0, 0); stA(0, 1); stB(1, 0); stB(1, 1);
    asm volatile("s_waitcnt vmcnt(4)" ::: "memory");
    BAR();
    RD_A2(afrX, 0, 0);   // A(0, m0-1) @ ab0

    for (int t = 0; t < NIT; ++t) {
        const int O  = 2 * t + 1;
        const int E2 = 2 * t + 2;
        const int O2 = 2 * t + 3;
        const int AO  = (O  & 1) * 32768;   // = 32768 (ab1)
        const int AE2 = (E2 & 1) * 32768;   // = 0     (ab0)
        const int BE  = ((2 * t) & 1) * 32768;  // 0 (bb0)
        const int BO  = (O & 1) * 32768;        // 32768 (bb1)

        // ---- P0 (tile E, m0-1; afrX): read B(E) [first use], afrY<-A(E,m2-3)
        RD_B8(BE);
        RD_A2(afrY, BE /*==0: ab0*/, 2);
        stA(O, 0);
        DO_MFMA(afrX, 0);
        BAR();

        // ---- P1 (m2-3; afrY): read afrX<-A(E,m4-5)
        RD_A2(afrX, 0, 4);
        stA(O, 1);
        DO_MFMA(afrY, 2);
        BAR();

        // ---- P2 (m4-5; afrX): read afrY<-A(E,m6-7); publish A(O)+B(O)
        RD_A2(afrY, 0, 6);
        stB(E2, 0);
        DO_MFMA(afrX, 4);
        VM2();
        BAR();

        // ---- P3 (m6-7; afrY): read afrX<-A(O,m0-1) (published at P2)
        RD_A2(afrX, AO, 0);
        stB(E2, 1);
        DO_MFMA(afrY, 6);
        BAR();

        // ---- P4 (tile O, m0-1; afrX): read B(O) [first use], afrY<-A(O,m2-3)
        RD_B8(BO);
        RD_A2(afrY, AO, 2);
        stA(E2, 0);
        DO_MFMA(afrX, 0);
        BAR();

        // ---- P5 (m2-3; afrY): read afrX<-A(O,m4-5)
        RD_A2(afrX, AO, 4);
        stA(E2, 1);
        DO_MFMA(afrY, 2);
        BAR();

        // ---- P6 (m4-5; afrX): read afrY<-A(O,m6-7); publish A(E2)+B(E2)
        RD_A2(afrY, AO, 6);
        stB(O2, 0);
        DO_MFMA(afrX, 4);
        VM2();
        BAR();

        // ---- P7 (m6-7; afrY): read afrX<-A(E2,m0-1) (published at P6)
        RD_A2(afrX, AE2, 0);
        stB(O2, 1);
        DO_MFMA(afrY, 6);
        BAR();
    }

    asm volatile("s_waitcnt vmcnt(0)" ::: "memory");
    __builtin_amdgcn_sched_barrier(0);

    // ---- epilogue
    if (EPI == 1) {
        const float inv_cnt = 1.0f / ((float)HH * (float)KK);
        const bool is_r = (bn < 8);
        const float scale = (is_r ? scales[0] : scales[1]) * inv_cnt;
        const float* bias = is_r ? b_r : b_z;
        #pragma unroll
        for (int m = 0; m < 8; m++) {
            #pragma unroll
            for (int n = 0; n < 4; n++) {
                const int col = bn * 256 + wc * 64 + n * 16 + (lane & 15);
                const int j = is_r ? col : col - 2048;
                const float bj = bias[j];
                #pragma unroll
                for (int i = 0; i < 4; i++) {
                    const int row = bm * 256 + wr * 128 + m * 16 + ((lane >> 4) << 2) + i;
                    float pre = acc[m][n][i] * scale + bj;
                    float sg = 1.0f / (1.0f + __expf(-pre));
                    if (is_r) {
                        float rh = sg * hidden[(size_t)row * HH + j];
                        combined2[(size_t)row * KK + 2048 + j] = __float2bfloat16(rh);
                    } else {
                        z_buf[(size_t)row * HH + j] = sg;
                    }
                }
            }
        }
    } else {
        float* pdst = (blockIdx.z == 0) ? part0 : part1;
        #pragma unroll
        for (int m = 0; m < 8; m++) {
            #pragma unroll
            for (int n = 0; n < 4; n++) {
                const int col = bn * 256 + wc * 64 + n * 16 + (lane & 15);
                #pragma unroll
                for (int i = 0; i < 4; i++) {
                    const int row = bm * 256 + wr * 128 + m * 16 + ((lane >> 4) << 2) + i;
                    pdst[(size_t)row * HH + col] = acc[m][n][i];
                }
            }
        }
    }
}

// ---------------------------------------------------------------------------
// combine: out = (1-z)*hidden + z*tanh((p0+p1)*scale_n + b_n)
// ---------------------------------------------------------------------------
__global__ __launch_bounds__(256) void combine(
    const float* __restrict__ p0, const float* __restrict__ p1,
    const float* __restrict__ z_buf, const float* __restrict__ hidden,
    const float* __restrict__ scales, const float* __restrict__ b_n,
    float* __restrict__ out)
{
    const float scale = scales[2] * (1.0f / ((float)HH * (float)KK));
    const int total4 = BB * HH / 4;
    const int tid = blockIdx.x * 256 + threadIdx.x;
    const int stride = gridDim.x * 256;

    for (int i = tid; i < total4; i += stride) {
        float4 a = reinterpret_cast<const float4*>(p0)[i];
        float4 b = reinterpret_cast<const float4*>(p1)[i];
        float4 z = reinterpret_cast<const float4*>(z_buf)[i];
        float4 h = reinterpret_cast<const float4*>(hidden)[i];
        float4 bn = reinterpret_cast<const float4*>(b_n)[(i * 4 & 2047) >> 2];
        float4 o;
        o.x = (1.0f - z.x) * h.x + z.x * tanhf((a.x + b.x) * scale + bn.x);
        o.y = (1.0f - z.y) * h.y + z.y * tanhf((a.y + b.y) * scale + bn.y);
        o.z = (1.0f - z.z) * h.z + z.z * tanhf((a.z + b.z) * scale + bn.z);
        o.w = (1.0f - z.w) * h.w + z.w * tanhf((a.w + b.w) * scale + bn.w);
        reinterpret_cast<float4*>(out)[i] = o;
    }
}

// ---------------------------------------------------------------------------
extern "C" void kernel_launch(void* const* d_in, const int* in_sizes, int n_in,
                              void* d_out, int out_size, void* d_ws, size_t ws_size,
                              hipStream_t stream) {
    const float* x      = (const float*)d_in[0];
    const float* hidden = (const float*)d_in[1];
    const float* w_r    = (const float*)d_in[2];
    const float* b_r    = (const float*)d_in[3];
    const float* w_z    = (const float*)d_in[4];
    const float* b_z    = (const float*)d_in[5];
    const float* w_n    = (const float*)d_in[6];
    const float* b_n    = (const float*)d_in[7];
    float* out = (float*)d_out;

    char* ws = (char*)d_ws;
    size_t off = 0;
    float* scales = (float*)(ws + off);                 off += 256;
    __hip_bfloat16* combined  = (__hip_bfloat16*)(ws + off); off += (size_t)BB * KK * 2;
    __hip_bfloat16* combined2 = (__hip_bfloat16*)(ws + off); off += (size_t)BB * KK * 2;
    __hip_bfloat16* sign_rz   = (__hip_bfloat16*)(ws + off); off += (size_t)2 * HH * KK * 2;
    __hip_bfloat16* sign_n    = (__hip_bfloat16*)(ws + off); off += (size_t)HH * KK * 2;
    float* z_buf = (float*)(ws + off);                  off += (size_t)BB * HH * 4;
    // split-K partials: slice 0 -> d_out (scratch until combine); slice 1
    // aliases sign_rz (dead after GEMM1, 64MB >= 32MB needed)
    float* part1 = (float*)sign_rz;

    hipMemsetAsync(scales, 0, 3 * sizeof(float), stream);

    prep_weights<<<dim3(512, 3), 256, 0, stream>>>(w_r, w_z, w_n,
                                                   sign_rz, sign_n, scales);
    prep_inputs<<<dim3(1024, 2), 256, 0, stream>>>(x, hidden, combined, combined2);

    // GEMM1: r||z  (N = 4096), full K, 256 blocks = 1/CU
    gemm8p<1, 32><<<dim3(16, 16, 1), 512, 0, stream>>>(
        combined, sign_rz, scales, b_r, b_z, hidden, z_buf, combined2,
        out, part1);

    // GEMM2: n  (N = 2048), split-K=2, 8x16x2 = 256 blocks = 1/CU
    gemm8p<2, 16><<<dim3(8, 16, 2), 512, 0, stream>>>(
        combined2, sign_n, scales, b_r, b_z, hidden, z_buf, combined2,
        out, part1);

    // fuse scale+bias+tanh+GRU blend
    combine<<<dim3(2048), 256, 0, stream>>>(out, part1, z_buf, hidden,
                                            scales, b_n, out);
}